// Round 8
// baseline (229.959 us; speedup 1.0000x reference)
//
#include <hip/hip_runtime.h>
#include <hip/hip_bf16.h>

// Problem: B=2, S=2048, E=1024, H=16, D=64, causal MHA, fp32 in/out.
#define B_ 2
#define S_ 2048
#define E_ 1024
#define H_ 16
#define D_ 64
#define QKV_N 3072
// SCALE * log2(e), folded into wq at cast time -> attn uses exp2f directly.
#define C2_ 0.18033688011112042f

typedef __attribute__((ext_vector_type(8))) unsigned short ushort8_t;
typedef __attribute__((ext_vector_type(8))) short short8_t;   // 8 bf16 MFMA frag
typedef __attribute__((ext_vector_type(4))) float f32x4;      // MFMA accum frag

__device__ __forceinline__ unsigned short f2b(float f) {
    union { float f; unsigned u; } x; x.f = f;
    unsigned r = x.u + 0x7FFFu + ((x.u >> 16) & 1u);
    return (unsigned short)(r >> 16);
}
__device__ __forceinline__ ushort2 pkbf(float a, float b) {
    union { __hip_bfloat162 h; ushort2 u; } c;
    c.h = __float22bfloat162_rn(make_float2(a, b));
    return c.u;
}
// async global->LDS, 16 B per lane. LDS base wave-uniform; HW adds lane*16.
__device__ __forceinline__ void glds16(const unsigned short* g, unsigned short* l) {
    __builtin_amdgcn_global_load_lds((const __attribute__((address_space(1))) void*)g,
                                     (__attribute__((address_space(3))) void*)l, 16, 0, 0);
}

// ---------------- fused cast: x + 4 weights, one launch ----------------
__global__ __launch_bounds__(256) void cast_all(const float* __restrict__ x,
                                                const float* __restrict__ wq,
                                                const float* __restrict__ wk,
                                                const float* __restrict__ wv,
                                                const float* __restrict__ wo,
                                                unsigned short* __restrict__ xb,
                                                unsigned short* __restrict__ wb) {
    int idx = blockIdx.x * 256 + threadIdx.x;
    const float* src; unsigned short* dst; float s = 1.f; int j;
    if (idx < 1048576) {
        src = x; dst = xb; j = idx;
    } else {
        j = idx - 1048576;
        int y = j >> 18;                       // block-uniform (aligned boundaries)
        src = (y == 0) ? wq : (y == 1) ? wk : (y == 2) ? wv : wo;
        dst = wb + (size_t)y * 1048576;
        j &= 262143;
        if (y == 0) s = C2_;
    }
    float4 v = ((const float4*)src)[j];
    ushort2 lo = pkbf(v.x * s, v.y * s), hi = pkbf(v.z * s, v.w * s);
    ((ushort4*)dst)[j] = make_ushort4(lo.x, lo.y, hi.x, hi.y);
}

// ---------------- bf16 GEMM, C = A * Bt^T, m97-style glds staging ----------------
// MODE: 0 = bf16 store, 1 = fp32 store, 2 = fp32 atomicAdd (split-K)
template <int TM, int MODE>
__device__ __forceinline__ void gemm_bt_body(const unsigned short* __restrict__ A,
                                             const unsigned short* __restrict__ Bt,
                                             void* __restrict__ Cout,
                                             int N, int K, int kbeg, int kend) {
    __shared__ unsigned short As[TM * 32];
    __shared__ unsigned short Bs[128 * 32];
    const int m0 = blockIdx.y * TM;
    const int n0 = blockIdx.x * 128;
    const int tid = threadIdx.x;
    const int wave = tid >> 6;
    const int lane = tid & 63;
    const int wm = (wave >> 1) * (TM / 2);
    const int wn = (wave & 1) * 64;
    const int quad = lane >> 4;
    const int l15 = lane & 15;
    constexpr int MI = TM / 32;

    f32x4 acc[MI][4] = {};

    const int srow = lane >> 2;
    const int scb  = (lane & 3) * 8;
    const unsigned short* gB0 = Bt + (size_t)(n0 + wave * 32 + srow) * K + scb;
    const unsigned short* gB1 = gB0 + (size_t)16 * K;
    unsigned short* lB0 = Bs + wave * 1024;
    unsigned short* lB1 = lB0 + 512;
    const unsigned short* gA0;
    const unsigned short* gA1 = nullptr;
    unsigned short* lA0;
    unsigned short* lA1 = nullptr;
    if (TM == 128) {
        gA0 = A + (size_t)(m0 + wave * 32 + srow) * K + scb;
        gA1 = gA0 + (size_t)16 * K;
        lA0 = As + wave * 1024; lA1 = lA0 + 512;
    } else {
        gA0 = A + (size_t)(m0 + wave * 16 + srow) * K + scb;
        lA0 = As + wave * 512;
    }

    for (int k0 = kbeg; k0 < kend; k0 += 32) {
        __syncthreads();
        glds16(gA0 + k0, lA0);
        if (TM == 128) glds16(gA1 + k0, lA1);
        glds16(gB0 + k0, lB0);
        glds16(gB1 + k0, lB1);
        __syncthreads();

        short8_t af[MI], bfv[4];
#pragma unroll
        for (int mi = 0; mi < MI; ++mi)
            af[mi] = *(const short8_t*)(&As[(wm + mi * 16 + l15) * 32 + quad * 8]);
#pragma unroll
        for (int ni = 0; ni < 4; ++ni)
            bfv[ni] = *(const short8_t*)(&Bs[(wn + ni * 16 + l15) * 32 + quad * 8]);
#pragma unroll
        for (int mi = 0; mi < MI; ++mi)
#pragma unroll
            for (int ni = 0; ni < 4; ++ni)
                acc[mi][ni] = __builtin_amdgcn_mfma_f32_16x16x32_bf16(
                    af[mi], bfv[ni], acc[mi][ni], 0, 0, 0);
    }

#pragma unroll
    for (int mi = 0; mi < MI; ++mi)
#pragma unroll
        for (int ni = 0; ni < 4; ++ni)
#pragma unroll
            for (int r = 0; r < 4; ++r) {
                int row = m0 + wm + mi * 16 + quad * 4 + r;
                int col = n0 + wn + ni * 16 + l15;
                float val = acc[mi][ni][r];
                if (MODE == 0)
                    ((unsigned short*)Cout)[(size_t)row * N + col] = f2b(val);
                else if (MODE == 1)
                    ((float*)Cout)[(size_t)row * N + col] = val;
                else
                    atomicAdd(&((float*)Cout)[(size_t)row * N + col], val);
            }
}

// Fused QKV: [4096,1024] x [3072,1024]^T -> [4096,3072] bf16.  768 blocks;
// (256,3) -> 3 blocks/CU so the whole grid co-resides.
__global__ __launch_bounds__(256, 3) void gemm_qkv(const unsigned short* __restrict__ xb,
                                                   const unsigned short* __restrict__ wqkv,
                                                   unsigned short* __restrict__ qkv) {
    gemm_bt_body<128, 0>(xb, wqkv, qkv, QKV_N, E_, 0, E_);
}

// Out-proj with split-K: z in {0,1} covers K halves; fp32 atomicAdd epilogue.
// TM=128 restores full MFMA:staging density; 512 blocks -> 2/CU.
__global__ __launch_bounds__(256, 2) void gemm_out(const unsigned short* __restrict__ a,
                                                   const unsigned short* __restrict__ wob,
                                                   float* __restrict__ c) {
    const int kbeg = blockIdx.z * 512;
    gemm_bt_body<128, 2>(a, wob, c, E_, E_, kbeg, kbeg + 512);
}

// ---------------- V transpose: fused qkv -> [B*H*D, S] ----------------
__global__ __launch_bounds__(256) void transpose_v(const unsigned short* __restrict__ qkv,
                                                   unsigned short* __restrict__ Vt) {
    __shared__ unsigned short T[64][72];
    const int b = blockIdx.z, h = blockIdx.y, kt = blockIdx.x * 64;
    const int r = threadIdx.x >> 2;
    const int g = (threadIdx.x & 3) * 16;
    const size_t goff = (size_t)(b * S_ + kt + r) * QKV_N + 2048 + h * D_ + g;
    ushort8_t v0 = *(const ushort8_t*)(qkv + goff);
    ushort8_t v1 = *(const ushort8_t*)(qkv + goff + 8);
    *(ushort8_t*)(&T[r][g])     = v0;
    *(ushort8_t*)(&T[r][g + 8]) = v1;
    __syncthreads();
    ushort8_t o0, o1;
#pragma unroll
    for (int i = 0; i < 8; ++i) { o0[i] = T[g + i][r]; o1[i] = T[g + 8 + i][r]; }
    unsigned short* op = Vt + ((size_t)((b * H_ + h) * D_ + r)) * S_ + kt + g;
    *(ushort8_t*)(op)     = o0;
    *(ushort8_t*)(op + 8) = o1;
}

// ---------------- MFMA causal flash attention v8 ----------------
// 256-thr block, 4 waves x 32 q-rows. Waves 0-1 = heavy chunk (31-c),
// waves 2-3 = light chunk c, sharing staged K/V (light kv-range subset).
// 32q/wave amortizes K/V frag reads over 2 q-subtiles (R5-verified body);
// (256,4) -> 4 blocks/CU: 16 waves/CU with 4 independent barrier groups.
__global__ __launch_bounds__(256, 4) void attn_kernel(const unsigned short* __restrict__ QKV,
                                                      const unsigned short* __restrict__ Vtg,
                                                      unsigned short* __restrict__ O) {
    __shared__ unsigned short Ks[64 * 64];      // [kv][d]  swizzled
    __shared__ unsigned short Vs[64 * 64];      // [d][kv]  swizzled
    __shared__ unsigned short Ps[4][32 * 64];   // per wave [q][kv] swizzled

    const int b = blockIdx.z, h = blockIdx.y;
    const int cp = blockIdx.x;                  // pair id 0..15
    const int tid = threadIdx.x;
    const int w = tid >> 6, lane = tid & 63;
    const int quad = lane >> 4, l15 = lane & 15;
    const int lx = l15 & 7;
    const int chunk = (w < 2) ? (31 - cp) : cp; // 64-q chunks, 32 per (b,h)
    const int Q0 = chunk * 64 + (w & 1) * 32;   // wave's 32 q rows

    // Q B-frags (pre-scaled by C2_ via wq), 2 subtiles
    short8_t bq[2][2];
#pragma unroll
    for (int qs = 0; qs < 2; ++qs) {
        const size_t qo = (size_t)(b * S_ + Q0 + qs * 16 + l15) * QKV_N + h * D_;
        bq[qs][0] = *(const short8_t*)(QKV + qo + quad * 8);
        bq[qs][1] = *(const short8_t*)(QKV + qo + 32 + quad * 8);
    }

    f32x4 Oacc[2][4] = {};
    float lsum[2] = {0.f, 0.f};
    const int qg[2] = {Q0 + l15, Q0 + 16 + l15};

    const int fo0 = ((quad) ^ lx) * 8;
    const int fo1 = ((4 + quad) ^ lx) * 8;
    const int krow = l15 * 64;
    int pwo[4];
#pragma unroll
    for (int tm = 0; tm < 4; ++tm)
        pwo[tm] = ((tm * 2 + (quad >> 1)) ^ lx) * 8 + (quad & 1) * 4;

    // staging (R5-verified map): K row=tid&63, blocks (tid>>6)*2+{0,1};
    //                            V row=tid>>2, blocks (tid&3)*2+{0,1}
    const int ksr = tid & 63;
    const int kb0 = (tid >> 6) * 2;
    const int vd  = tid >> 2;
    const int vb0 = (tid & 3) * 2;
    const unsigned short* Kbase = QKV + (size_t)(b * S_) * QKV_N + 1024 + h * D_;
    const unsigned short* Vbase = Vtg + (size_t)((b * H_ + h) * D_) * S_;

    const int ntiles = 32 - cp;                 // heavy chunk needs tiles 0..31-cp
    for (int t = 0; t < ntiles; ++t) {
        const int kt = t * 64;
        const unsigned short* kg = Kbase + (size_t)(kt + ksr) * QKV_N + kb0 * 8;
        ushort8_t k0 = *(const ushort8_t*)(kg);
        ushort8_t k1 = *(const ushort8_t*)(kg + 8);
        const unsigned short* vp = Vbase + (size_t)vd * S_ + kt + vb0 * 8;
        ushort8_t v0 = *(const ushort8_t*)(vp);
        ushort8_t v1 = *(const ushort8_t*)(vp + 8);
        __syncthreads();   // previous tile's consumers done
        *(ushort8_t*)(&Ks[ksr * 64 + ((kb0)     ^ (ksr & 7)) * 8]) = k0;
        *(ushort8_t*)(&Ks[ksr * 64 + ((kb0 + 1) ^ (ksr & 7)) * 8]) = k1;
        *(ushort8_t*)(&Vs[vd * 64 + ((vb0)     ^ (vd & 7)) * 8]) = v0;
        *(ushort8_t*)(&Vs[vd * 64 + ((vb0 + 1) ^ (vd & 7)) * 8]) = v1;
        __syncthreads();

        if (kt > Q0 + 31) continue;             // beyond this wave's causal range
        const bool h2 = (kt < Q0);              // second kv-half (32..63) live?
        const int tmmax = h2 ? 4 : 2;

        if (kt + 63 <= Q0) {
            // ---- full tile: no mask ----
#pragma unroll
            for (int tm = 0; tm < 4; ++tm) {
                short8_t ak0 = *(const short8_t*)(&Ks[tm * 1024 + krow + fo0]);
                short8_t ak1 = *(const short8_t*)(&Ks[tm * 1024 + krow + fo1]);
#pragma unroll
                for (int qs = 0; qs < 2; ++qs) {
                    f32x4 st = {0.f, 0.f, 0.f, 0.f};
                    st = __builtin_amdgcn_mfma_f32_16x16x32_bf16(ak0, bq[qs][0], st, 0, 0, 0);
                    st = __builtin_amdgcn_mfma_f32_16x16x32_bf16(ak1, bq[qs][1], st, 0, 0, 0);
                    float p0 = exp2f(st[0]), p1 = exp2f(st[1]);
                    float p2 = exp2f(st[2]), p3 = exp2f(st[3]);
                    lsum[qs] += (p0 + p1) + (p2 + p3);
                    ushort2 a = pkbf(p0, p1), c2 = pkbf(p2, p3);
                    *(ushort4*)(&Ps[w][(qs * 16 + l15) * 64 + pwo[tm]]) =
                        make_ushort4(a.x, a.y, c2.x, c2.y);
                }
            }
        } else {
            // ---- diagonal-area: mask kv > q ----
            for (int tm = 0; tm < tmmax; ++tm) {
                short8_t ak0 = *(const short8_t*)(&Ks[tm * 1024 + krow + fo0]);
                short8_t ak1 = *(const short8_t*)(&Ks[tm * 1024 + krow + fo1]);
                const int kvb = kt + tm * 16 + quad * 4;
#pragma unroll
                for (int qs = 0; qs < 2; ++qs) {
                    f32x4 st = {0.f, 0.f, 0.f, 0.f};
                    st = __builtin_amdgcn_mfma_f32_16x16x32_bf16(ak0, bq[qs][0], st, 0, 0, 0);
                    st = __builtin_amdgcn_mfma_f32_16x16x32_bf16(ak1, bq[qs][1], st, 0, 0, 0);
                    float p0 = (kvb     > qg[qs]) ? 0.f : exp2f(st[0]);
                    float p1 = (kvb + 1 > qg[qs]) ? 0.f : exp2f(st[1]);
                    float p2 = (kvb + 2 > qg[qs]) ? 0.f : exp2f(st[2]);
                    float p3 = (kvb + 3 > qg[qs]) ? 0.f : exp2f(st[3]);
                    lsum[qs] += (p0 + p1) + (p2 + p3);
                    ushort2 a = pkbf(p0, p1), c2 = pkbf(p2, p3);
                    *(ushort4*)(&Ps[w][(qs * 16 + l15) * 64 + pwo[tm]]) =
                        make_ushort4(a.x, a.y, c2.x, c2.y);
                }
            }
        }

        // ---- O += P V ----
#pragma unroll
        for (int kh = 0; kh < 2; ++kh) {
            if (kh == 1 && !h2) break;
            const int fo = kh ? fo1 : fo0;
            short8_t bv[4];
#pragma unroll
            for (int tn = 0; tn < 4; ++tn)
                bv[tn] = *(const short8_t*)(&Vs[tn * 1024 + krow + fo]);
#pragma unroll
            for (int qs = 0; qs < 2; ++qs) {
                short8_t ap = *(const short8_t*)(&Ps[w][(qs * 16 + l15) * 64 + fo]);
#pragma unroll
                for (int tn = 0; tn < 4; ++tn)
                    Oacc[qs][tn] = __builtin_amdgcn_mfma_f32_16x16x32_bf16(
                        ap, bv[tn], Oacc[qs][tn], 0, 0, 0);
            }
        }
    }

    // ---- epilogue: normalize, store bf16 ----
#pragma unroll
    for (int qs = 0; qs < 2; ++qs) {
        float l = lsum[qs];
        l += __shfl_xor(l, 16);
        l += __shfl_xor(l, 32);
        float inv = 1.f / l;
        float lir[4];
#pragma unroll
        for (int r = 0; r < 4; ++r)
            lir[r] = __shfl(inv, quad * 4 + r);
#pragma unroll
        for (int tn = 0; tn < 4; ++tn)
#pragma unroll
            for (int r = 0; r < 4; ++r) {
                int row = Q0 + qs * 16 + quad * 4 + r;
                O[(size_t)(b * S_ + row) * E_ + h * D_ + tn * 16 + l15] =
                    f2b(Oacc[qs][tn][r] * lir[r]);
            }
    }
}

// ---------------- launch ----------------
extern "C" void kernel_launch(void* const* d_in, const int* in_sizes, int n_in,
                              void* d_out, int out_size, void* d_ws, size_t ws_size,
                              hipStream_t stream) {
    const float* x  = (const float*)d_in[0];
    const float* wq = (const float*)d_in[1];
    const float* wk = (const float*)d_in[2];
    const float* wv = (const float*)d_in[3];
    const float* wo = (const float*)d_in[4];
    float* out = (float*)d_out;

    unsigned short* ws   = (unsigned short*)d_ws;
    unsigned short* xb   = ws;                   // [0, 4194304)   reused as vt
    unsigned short* wqkv = ws + 4194304;         // 3 x 1048576 (wq|wk|wv)
    unsigned short* wob  = ws + 7340032;         // 1048576
    unsigned short* qkvb = ws + 8388608;         // 4096 x 3072 = 12582912
    unsigned short* ab   = ws + 20971520;        // 4194304
    unsigned short* vt   = xb;

    cast_all<<<8192, 256, 0, stream>>>(x, wq, wk, wv, wo, xb, wqkv);
    gemm_qkv<<<dim3(24, 32), 256, 0, stream>>>(xb, wqkv, qkvb);
    transpose_v<<<dim3(32, 16, 2), 256, 0, stream>>>(qkvb, vt);
    attn_kernel<<<dim3(16, 16, 2), 256, 0, stream>>>(qkvb, vt, ab);
    hipMemsetAsync(out, 0, (size_t)out_size * sizeof(float), stream);
    gemm_out<<<dim3(8, 32, 2), 256, 0, stream>>>(ab, wob, out);
}

// Round 9
// 181.410 us; speedup vs baseline: 1.2676x; 1.2676x over previous
//
#include <hip/hip_runtime.h>
#include <hip/hip_bf16.h>

// Problem: B=2, S=2048, E=1024, H=16, D=64, causal MHA, fp32 in/out.
#define B_ 2
#define S_ 2048
#define E_ 1024
#define H_ 16
#define D_ 64
#define QKV_N 3072
// SCALE * log2(e), folded into wq at cast time -> attn uses exp2f directly.
#define C2_ 0.18033688011112042f

typedef __attribute__((ext_vector_type(8))) unsigned short ushort8_t;
typedef __attribute__((ext_vector_type(8))) short short8_t;   // 8 bf16 MFMA frag
typedef __attribute__((ext_vector_type(4))) float f32x4;      // MFMA accum frag

__device__ __forceinline__ unsigned short f2b(float f) {
    union { float f; unsigned u; } x; x.f = f;
    unsigned r = x.u + 0x7FFFu + ((x.u >> 16) & 1u);
    return (unsigned short)(r >> 16);
}
__device__ __forceinline__ ushort2 pkbf(float a, float b) {
    union { __hip_bfloat162 h; ushort2 u; } c;
    c.h = __float22bfloat162_rn(make_float2(a, b));
    return c.u;
}
// async global->LDS, 16 B per lane. LDS base wave-uniform; HW adds lane*16.
__device__ __forceinline__ void glds16(const unsigned short* g, unsigned short* l) {
    __builtin_amdgcn_global_load_lds((const __attribute__((address_space(1))) void*)g,
                                     (__attribute__((address_space(3))) void*)l, 16, 0, 0);
}

// ---------------- fused cast: x + 4 weights, one launch ----------------
__global__ __launch_bounds__(256) void cast_all(const float* __restrict__ x,
                                                const float* __restrict__ wq,
                                                const float* __restrict__ wk,
                                                const float* __restrict__ wv,
                                                const float* __restrict__ wo,
                                                unsigned short* __restrict__ xb,
                                                unsigned short* __restrict__ wb) {
    int idx = blockIdx.x * 256 + threadIdx.x;
    const float* src; unsigned short* dst; float s = 1.f; int j;
    if (idx < 1048576) {
        src = x; dst = xb; j = idx;
    } else {
        j = idx - 1048576;
        int y = j >> 18;                       // block-uniform (aligned boundaries)
        src = (y == 0) ? wq : (y == 1) ? wk : (y == 2) ? wv : wo;
        dst = wb + (size_t)y * 1048576;
        j &= 262143;
        if (y == 0) s = C2_;
    }
    float4 v = ((const float4*)src)[j];
    ushort2 lo = pkbf(v.x * s, v.y * s), hi = pkbf(v.z * s, v.w * s);
    ((ushort4*)dst)[j] = make_ushort4(lo.x, lo.y, hi.x, hi.y);
}

// ---------------- bf16 GEMM, C = A * Bt^T, BK=64 (two 32-K halves/barrier) ----
// Physical LDS layout of each half identical to the verified [TM][32] pattern;
// half 1 lives at offset TM*32 (Bs: 128*32). 32 MFMA per barrier pair (TM=128).
template <int TM, bool OUT_BF16>
__device__ __forceinline__ void gemm_bt_body(const unsigned short* __restrict__ A,
                                             const unsigned short* __restrict__ Bt,
                                             void* __restrict__ Cout,
                                             int N, int K) {
    __shared__ unsigned short As[2 * TM * 32];
    __shared__ unsigned short Bs[2 * 128 * 32];
    const int m0 = blockIdx.y * TM;
    const int n0 = blockIdx.x * 128;
    const int tid = threadIdx.x;
    const int wave = tid >> 6;
    const int lane = tid & 63;
    const int wm = (wave >> 1) * (TM / 2);
    const int wn = (wave & 1) * 64;
    const int quad = lane >> 4;
    const int l15 = lane & 15;
    constexpr int MI = TM / 32;

    f32x4 acc[MI][4] = {};

    const int srow = lane >> 2;
    const int scb  = (lane & 3) * 8;
    const unsigned short* gB0 = Bt + (size_t)(n0 + wave * 32 + srow) * K + scb;
    const unsigned short* gB1 = gB0 + (size_t)16 * K;
    unsigned short* lB0 = Bs + wave * 1024;
    unsigned short* lB1 = lB0 + 512;
    const unsigned short* gA0;
    const unsigned short* gA1 = nullptr;
    unsigned short* lA0;
    unsigned short* lA1 = nullptr;
    if (TM == 128) {
        gA0 = A + (size_t)(m0 + wave * 32 + srow) * K + scb;
        gA1 = gA0 + (size_t)16 * K;
        lA0 = As + wave * 1024; lA1 = lA0 + 512;
    } else {
        gA0 = A + (size_t)(m0 + wave * 16 + srow) * K + scb;
        lA0 = As + wave * 512;
    }

    for (int k0 = 0; k0 < K; k0 += 64) {
        __syncthreads();
        // half 0 (k0) and half 1 (k0+32); half-1 LDS region at +TM*32 / +128*32
        glds16(gA0 + k0, lA0);
        glds16(gA0 + k0 + 32, lA0 + TM * 32);
        if (TM == 128) {
            glds16(gA1 + k0, lA1);
            glds16(gA1 + k0 + 32, lA1 + TM * 32);
        }
        glds16(gB0 + k0, lB0);
        glds16(gB0 + k0 + 32, lB0 + 128 * 32);
        glds16(gB1 + k0, lB1);
        glds16(gB1 + k0 + 32, lB1 + 128 * 32);
        __syncthreads();

#pragma unroll
        for (int h = 0; h < 2; ++h) {
            const unsigned short* ah = As + h * TM * 32;
            const unsigned short* bh = Bs + h * 128 * 32;
            short8_t af[MI], bfv[4];
#pragma unroll
            for (int mi = 0; mi < MI; ++mi)
                af[mi] = *(const short8_t*)(&ah[(wm + mi * 16 + l15) * 32 + quad * 8]);
#pragma unroll
            for (int ni = 0; ni < 4; ++ni)
                bfv[ni] = *(const short8_t*)(&bh[(wn + ni * 16 + l15) * 32 + quad * 8]);
#pragma unroll
            for (int mi = 0; mi < MI; ++mi)
#pragma unroll
                for (int ni = 0; ni < 4; ++ni)
                    acc[mi][ni] = __builtin_amdgcn_mfma_f32_16x16x32_bf16(
                        af[mi], bfv[ni], acc[mi][ni], 0, 0, 0);
        }
    }

#pragma unroll
    for (int mi = 0; mi < MI; ++mi)
#pragma unroll
        for (int ni = 0; ni < 4; ++ni)
#pragma unroll
            for (int r = 0; r < 4; ++r) {
                int row = m0 + wm + mi * 16 + quad * 4 + r;
                int col = n0 + wn + ni * 16 + l15;
                float val = acc[mi][ni][r];
                if (OUT_BF16)
                    ((unsigned short*)Cout)[(size_t)row * N + col] = f2b(val);
                else
                    ((float*)Cout)[(size_t)row * N + col] = val;
            }
}

// Fused QKV: [4096,1024] x [3072,1024]^T -> [4096,3072] bf16.  768 blocks;
// (256,3) -> 3 blocks/CU so the whole grid co-resides.
__global__ __launch_bounds__(256, 3) void gemm_qkv(const unsigned short* __restrict__ xb,
                                                   const unsigned short* __restrict__ wqkv,
                                                   unsigned short* __restrict__ qkv) {
    gemm_bt_body<128, true>(xb, wqkv, qkv, QKV_N, E_);
}

// Out-proj: TM=64, 512 blocks -> 2/CU (R7 config, + BK=64 unroll).
__global__ __launch_bounds__(256, 2) void gemm_out(const unsigned short* __restrict__ a,
                                                   const unsigned short* __restrict__ wob,
                                                   float* __restrict__ c) {
    gemm_bt_body<64, false>(a, wob, c, E_, E_);
}

// ---------------- V transpose: fused qkv -> [B*H*D, S] ----------------
__global__ __launch_bounds__(256) void transpose_v(const unsigned short* __restrict__ qkv,
                                                   unsigned short* __restrict__ Vt) {
    __shared__ unsigned short T[64][72];
    const int b = blockIdx.z, h = blockIdx.y, kt = blockIdx.x * 64;
    const int r = threadIdx.x >> 2;
    const int g = (threadIdx.x & 3) * 16;
    const size_t goff = (size_t)(b * S_ + kt + r) * QKV_N + 2048 + h * D_ + g;
    ushort8_t v0 = *(const ushort8_t*)(qkv + goff);
    ushort8_t v1 = *(const ushort8_t*)(qkv + goff + 8);
    *(ushort8_t*)(&T[r][g])     = v0;
    *(ushort8_t*)(&T[r][g + 8]) = v1;
    __syncthreads();
    ushort8_t o0, o1;
#pragma unroll
    for (int i = 0; i < 8; ++i) { o0[i] = T[g + i][r]; o1[i] = T[g + 8 + i][r]; }
    unsigned short* op = Vt + ((size_t)((b * H_ + h) * D_ + r)) * S_ + kt + g;
    *(ushort8_t*)(op)     = o0;
    *(ushort8_t*)(op + 8) = o1;
}

// ---------------- MFMA causal flash attention v9 ----------------
// R7 core (verified 51.9us) + double-buffered 128-kv outer tiles: two 64-kv
// sub-tiles (R7's exact per-tile layout each) staged behind ONE barrier pair,
// then R7's compute body runs on each. Barrier events halve. Ps is per-wave
// (written+read by same wave, no barrier needed). LDS 48KB, 512thr, 2 blk/CU.
__global__ __launch_bounds__(512, 4) void attn_kernel(const unsigned short* __restrict__ QKV,
                                                      const unsigned short* __restrict__ Vtg,
                                                      unsigned short* __restrict__ O) {
    __shared__ unsigned short Ks[2][64 * 64];   // [sub][kv][d]  swizzled
    __shared__ unsigned short Vs[2][64 * 64];   // [sub][d][kv]  swizzled
    __shared__ unsigned short Ps[8][16 * 64];   // per wave [q][kv] swizzled

    const int b = blockIdx.z, h = blockIdx.y;
    const int c = blockIdx.x;                   // pair id 0..15
    const int tid = threadIdx.x;
    const int w = tid >> 6, lane = tid & 63;
    const int quad = lane >> 4, l15 = lane & 15;
    const int lx = l15 & 7;
    // wave-group mapping: w<4 -> heavy chunk 31-c, w>=4 -> light chunk c
    const int chunk = (w < 4) ? (31 - c) : c;
    const int Q0 = chunk * 64 + (w & 3) * 16;   // wave's 16 q rows

    // Q B-frags (pre-scaled by C2_ via wq)
    const size_t qo = (size_t)(b * S_ + Q0 + l15) * QKV_N + h * D_;
    short8_t bq0 = *(const short8_t*)(QKV + qo + quad * 8);
    short8_t bq1 = *(const short8_t*)(QKV + qo + 32 + quad * 8);

    f32x4 Oacc[4] = {};
    float lsum = 0.f;
    const int qg = Q0 + l15;

    const int fo0 = ((quad) ^ lx) * 8;
    const int fo1 = ((4 + quad) ^ lx) * 8;
    const int krow = l15 * 64;
    int pwo[4];
#pragma unroll
    for (int tm = 0; tm < 4; ++tm)
        pwo[tm] = ((tm * 2 + (quad >> 1)) ^ lx) * 8 + (quad & 1) * 4;

    // staging: 512 threads, per sub-tile 1x16B K + 1x16B V each.
    const int srow = tid >> 3;
    const int scb  = tid & 7;
    const int swz  = (scb ^ (srow & 7)) * 8;
    const unsigned short* Kbase = QKV + (size_t)(b * S_) * QKV_N + 1024 + h * D_;
    const unsigned short* Vbase = Vtg + (size_t)((b * H_ + h) * D_) * S_;

    const int ntiles = 32 - c;                  // 64-kv tiles heavy chunk needs
    const int nT = (ntiles + 1) >> 1;           // 128-kv outer tiles
    for (int t = 0; t < nT; ++t) {
        const int kt0 = t * 128;
        // global loads for both sub-tiles (latency overlapped with prev compute)
        ushort8_t ka = *(const ushort8_t*)(Kbase + (size_t)(kt0 + srow) * QKV_N + scb * 8);
        ushort8_t kb = *(const ushort8_t*)(Kbase + (size_t)(kt0 + 64 + srow) * QKV_N + scb * 8);
        ushort8_t va = *(const ushort8_t*)(Vbase + (size_t)srow * S_ + kt0 + scb * 8);
        ushort8_t vb = *(const ushort8_t*)(Vbase + (size_t)srow * S_ + kt0 + 64 + scb * 8);
        __syncthreads();   // previous outer tile's consumers done
        *(ushort8_t*)(&Ks[0][srow * 64 + swz]) = ka;
        *(ushort8_t*)(&Ks[1][srow * 64 + swz]) = kb;
        *(ushort8_t*)(&Vs[0][srow * 64 + swz]) = va;
        *(ushort8_t*)(&Vs[1][srow * 64 + swz]) = vb;
        __syncthreads();

#pragma unroll
        for (int s = 0; s < 2; ++s) {
            const int kt = kt0 + s * 64;
            if (kt > Q0 + 15) continue;         // beyond this wave's causal range
            const bool h2 = (kt + 32 <= Q0 + 15);

            if (kt + 63 <= Q0) {
                // ---- full tile: no mask ----
#pragma unroll
                for (int tm = 0; tm < 4; ++tm) {
                    short8_t ak0 = *(const short8_t*)(&Ks[s][tm * 1024 + krow + fo0]);
                    short8_t ak1 = *(const short8_t*)(&Ks[s][tm * 1024 + krow + fo1]);
                    f32x4 st = {0.f, 0.f, 0.f, 0.f};
                    st = __builtin_amdgcn_mfma_f32_16x16x32_bf16(ak0, bq0, st, 0, 0, 0);
                    st = __builtin_amdgcn_mfma_f32_16x16x32_bf16(ak1, bq1, st, 0, 0, 0);
                    float p0 = exp2f(st[0]), p1 = exp2f(st[1]);
                    float p2 = exp2f(st[2]), p3 = exp2f(st[3]);
                    lsum += (p0 + p1) + (p2 + p3);
                    ushort2 a = pkbf(p0, p1), c2 = pkbf(p2, p3);
                    *(ushort4*)(&Ps[w][krow + pwo[tm]]) = make_ushort4(a.x, a.y, c2.x, c2.y);
                }
            } else {
                // ---- diagonal-area: mask kv > q; zero dead-but-read blocks ----
                const int need = h2 ? 4 : 2;
                for (int tm = 0; tm < need; ++tm) {
                    if (kt + tm * 16 <= Q0 + 15) {
                        short8_t ak0 = *(const short8_t*)(&Ks[s][tm * 1024 + krow + fo0]);
                        short8_t ak1 = *(const short8_t*)(&Ks[s][tm * 1024 + krow + fo1]);
                        f32x4 st = {0.f, 0.f, 0.f, 0.f};
                        st = __builtin_amdgcn_mfma_f32_16x16x32_bf16(ak0, bq0, st, 0, 0, 0);
                        st = __builtin_amdgcn_mfma_f32_16x16x32_bf16(ak1, bq1, st, 0, 0, 0);
                        const int kvb = kt + tm * 16 + quad * 4;
                        float p0 = (kvb     > qg) ? 0.f : exp2f(st[0]);
                        float p1 = (kvb + 1 > qg) ? 0.f : exp2f(st[1]);
                        float p2 = (kvb + 2 > qg) ? 0.f : exp2f(st[2]);
                        float p3 = (kvb + 3 > qg) ? 0.f : exp2f(st[3]);
                        lsum += (p0 + p1) + (p2 + p3);
                        ushort2 a = pkbf(p0, p1), c2 = pkbf(p2, p3);
                        *(ushort4*)(&Ps[w][krow + pwo[tm]]) = make_ushort4(a.x, a.y, c2.x, c2.y);
                    } else {
                        *(ushort4*)(&Ps[w][krow + pwo[tm]]) = make_ushort4(0, 0, 0, 0);
                    }
                }
            }

            // ---- O += P V ----
#pragma unroll
            for (int kh = 0; kh < 2; ++kh) {
                if (kh == 1 && !h2) break;
                const int fo = kh ? fo1 : fo0;
                short8_t bv[4];
#pragma unroll
                for (int tn = 0; tn < 4; ++tn)
                    bv[tn] = *(const short8_t*)(&Vs[s][tn * 1024 + krow + fo]);
                short8_t ap = *(const short8_t*)(&Ps[w][krow + fo]);
#pragma unroll
                for (int tn = 0; tn < 4; ++tn)
                    Oacc[tn] = __builtin_amdgcn_mfma_f32_16x16x32_bf16(
                        ap, bv[tn], Oacc[tn], 0, 0, 0);
            }
        }
    }

    // ---- epilogue: normalize, store bf16 ----
    float l = lsum;
    l += __shfl_xor(l, 16);
    l += __shfl_xor(l, 32);
    float inv = 1.f / l;
    float lir[4];
#pragma unroll
    for (int r = 0; r < 4; ++r)
        lir[r] = __shfl(inv, quad * 4 + r);
#pragma unroll
    for (int tn = 0; tn < 4; ++tn)
#pragma unroll
        for (int r = 0; r < 4; ++r) {
            int row = Q0 + quad * 4 + r;
            O[(size_t)(b * S_ + row) * E_ + h * D_ + tn * 16 + l15] =
                f2b(Oacc[tn][r] * lir[r]);
        }
}

// ---------------- launch ----------------
extern "C" void kernel_launch(void* const* d_in, const int* in_sizes, int n_in,
                              void* d_out, int out_size, void* d_ws, size_t ws_size,
                              hipStream_t stream) {
    const float* x  = (const float*)d_in[0];
    const float* wq = (const float*)d_in[1];
    const float* wk = (const float*)d_in[2];
    const float* wv = (const float*)d_in[3];
    const float* wo = (const float*)d_in[4];
    float* out = (float*)d_out;

    unsigned short* ws   = (unsigned short*)d_ws;
    unsigned short* xb   = ws;                   // [0, 4194304)   reused as vt
    unsigned short* wqkv = ws + 4194304;         // 3 x 1048576 (wq|wk|wv)
    unsigned short* wob  = ws + 7340032;         // 1048576
    unsigned short* qkvb = ws + 8388608;         // 4096 x 3072 = 12582912
    unsigned short* ab   = ws + 20971520;        // 4194304
    unsigned short* vt   = xb;

    cast_all<<<8192, 256, 0, stream>>>(x, wq, wk, wv, wo, xb, wqkv);
    gemm_qkv<<<dim3(24, 32), 256, 0, stream>>>(xb, wqkv, qkvb);
    transpose_v<<<dim3(32, 16, 2), 256, 0, stream>>>(qkvb, vt);
    attn_kernel<<<dim3(16, 16, 2), 512, 0, stream>>>(qkvb, vt, ab);
    gemm_out<<<dim3(8, 64), 256, 0, stream>>>(ab, wob, out);
}